// Round 5
// baseline (722.757 us; speedup 1.0000x reference)
//
#include <hip/hip_runtime.h>
#include <math.h>

typedef __attribute__((ext_vector_type(8))) short short8;
typedef __attribute__((ext_vector_type(4))) float f32x4;

#define NCB 4
#define NE 1024
#define DIM 64
#define HW 16384
#define NPIX 131072
#define NWAVES 4096            // 1024 blocks * 4 waves
#define MSE_DENOM 8388608.0f   // NPIX*DIM
#define EPSF 1e-5f
#define CHUNK_BYTES 24576      // 3 splits * 64 codes * 64 dims * 2B
#define CHUNK_SHORTS 12288

__device__ __forceinline__ unsigned short f2bf(float x) {  // RNE fp32->bf16
    unsigned u = __float_as_uint(x);
    u += 0x7fffu + ((u >> 16) & 1u);
    return (unsigned short)(u >> 16);
}
__device__ __forceinline__ float bf2f(unsigned short h) {  // exact bf16->fp32
    return __uint_as_float(((unsigned)h) << 16);
}

// ------------- kernel 0: -0.5*||e||^2 per code (fp32, exact) -------------
__global__ __launch_bounds__(64) void rvq_norms(const float* __restrict__ cb,
                                                float* __restrict__ nrmh) {
    int code = blockIdx.x * 64 + threadIdx.x;  // 0..4095
    const float4* row = reinterpret_cast<const float4*>(cb + (size_t)code * DIM);
    float s0 = 0.f, s1 = 0.f, s2 = 0.f, s3 = 0.f;
#pragma unroll
    for (int k = 0; k < 16; ++k) {
        float4 v = row[k];
        s0 = fmaf(v.x, v.x, s0); s1 = fmaf(v.y, v.y, s1);
        s2 = fmaf(v.z, v.z, s2); s3 = fmaf(v.w, v.w, s3);
    }
    nrmh[code] = -0.5f * ((s0 + s1) + (s2 + s3));
}

// ------------- kernel 0b: pre-split codebook -> swizzled bf16x3 image ----
// One block per (codebook i, chunk c). Produces the EXACT byte image the
// main kernel's LDS chunk buffer holds (incl. XOR swizzle), so main-loop
// staging is a linear 24KB copy with zero split VALU.
__global__ __launch_bounds__(256) void rvq_presplit(const float* __restrict__ cb,
                                                    unsigned short* __restrict__ gB) {
    int blk = blockIdx.x;            // i*16 + c
    int tid = threadIdx.x;
    int code = tid >> 2, dg = tid & 3;
    int c0 = (blk & 15) << 6;
    int i  = blk >> 4;
    const float4* s4 = reinterpret_cast<const float4*>(
        cb + ((size_t)i * NE + c0 + code) * DIM + dg * 16);
    float v[16];
    {
        float4 q;
        q = s4[0]; v[0]=q.x; v[1]=q.y; v[2]=q.z; v[3]=q.w;
        q = s4[1]; v[4]=q.x; v[5]=q.y; v[6]=q.z; v[7]=q.w;
        q = s4[2]; v[8]=q.x; v[9]=q.y; v[10]=q.z; v[11]=q.w;
        q = s4[3]; v[12]=q.x; v[13]=q.y; v[14]=q.z; v[15]=q.w;
    }
    char* outc = reinterpret_cast<char*>(gB + (size_t)blk * CHUNK_SHORTS);
    int linbase = code * 128 + dg * 32;
    int sw = (code & 7) << 4;
#pragma unroll
    for (int h = 0; h < 2; ++h) {
        short8 p1, p2, p3;
#pragma unroll
        for (int e = 0; e < 8; ++e) {
            float t = v[h * 8 + e];
            unsigned short u1 = f2bf(t); t -= bf2f(u1);
            unsigned short u2 = f2bf(t); t -= bf2f(u2);
            unsigned short u3 = f2bf(t);
            p1[e] = (short)u1; p2[e] = (short)u2; p3[e] = (short)u3;
        }
        int a = (linbase + h * 16) ^ sw;
        *reinterpret_cast<short8*>(outc + a)         = p1;
        *reinterpret_cast<short8*>(outc + 8192 + a)  = p2;
        *reinterpret_cast<short8*>(outc + 16384 + a) = p3;
    }
}

// ------------- kernel 1: MFMA RVQ, double-buffered pre-split staging -----
// 1024 blocks x 4 waves; wave owns 32 pixels (2 16-row A-tiles). Per chunk:
// issue next chunk's 6 dwordx4 loads (T14 issue-early), compute current
// chunk (24 ds_read_b128 + 96 MFMA + max-scan), barrier, write-late the
// staged regs into the alternate LDS buffer. Distances compared as
// s = r.e - 0.5||e||^2 (argmax s == argmin dist, exact), ascending-code
// strict-> scan + idx tie-break reduce = jnp.argmin first-min semantics.
// Numerics bit-identical to the validated R4 kernel.
__global__ __launch_bounds__(256, 2) void rvq_main(
    const float* __restrict__ z, const unsigned short* __restrict__ gB,
    const float* __restrict__ nrmh, const float* __restrict__ cb,
    float* __restrict__ out_zq, float* __restrict__ out_idx,
    unsigned* __restrict__ hist, float* __restrict__ msePartial)
{
    __shared__ uint4 sB[2][CHUNK_BYTES / 16];   // 48 KB double buffer
    __shared__ int   sBest[4][32];

    const int tid  = threadIdx.x;
    const int lane = tid & 63;
    const int wid  = tid >> 6;
    const int col  = lane & 15;   // A-row within tile / D-col (code)
    const int g    = lane >> 4;   // k-group (8 dims) / D row-group
    const int blockPix = blockIdx.x * 128;
    char* sBase = reinterpret_cast<char*>(sB);

    int pf[2]; size_t zb[2];
#pragma unroll
    for (int m = 0; m < 2; ++m) {
        pf[m] = blockPix + wid * 32 + m * 16 + col;
        zb[m] = (size_t)(pf[m] >> 14) * 1048576 + (size_t)(pf[m] & 16383);
    }

    float r[2][2][8];   // [m][kh][e], dim = kh*32 + g*8 + e
#pragma unroll
    for (int m = 0; m < 2; ++m)
#pragma unroll
        for (int kh = 0; kh < 2; ++kh)
#pragma unroll
            for (int e = 0; e < 8; ++e)
                r[m][kh][e] = z[zb[m] + (size_t)(kh * 32 + g * 8 + e) * HW];

    for (int i = 0; i < NCB; ++i) {
        const char* gBi = reinterpret_cast<const char*>(gB) + (size_t)i * 16 * CHUNK_BYTES;
        const float* nrm_i = nrmh + i * NE;

        // bf16x3 split of r -> A-frags (32 values, once per codebook)
        short8 A[3][2][2];
#pragma unroll
        for (int m = 0; m < 2; ++m)
#pragma unroll
            for (int kh = 0; kh < 2; ++kh)
#pragma unroll
                for (int e = 0; e < 8; ++e) {
                    float t = r[m][kh][e];
                    unsigned short u1 = f2bf(t); t -= bf2f(u1);
                    unsigned short u2 = f2bf(t); t -= bf2f(u2);
                    unsigned short u3 = f2bf(t);
                    A[0][m][kh][e] = (short)u1;
                    A[1][m][kh][e] = (short)u2;
                    A[2][m][kh][e] = (short)u3;
                }

        // prologue: stage chunk 0 into buffer 0
        uint4 st[6];
#pragma unroll
        for (int k = 0; k < 6; ++k)
            st[k] = *reinterpret_cast<const uint4*>(gBi + tid * 16 + k * 4096);
#pragma unroll
        for (int k = 0; k < 6; ++k)
            *reinterpret_cast<uint4*>(sBase + tid * 16 + k * 4096) = st[k];
        __syncthreads();

        float maxv[2][4]; int maxi[2][4];
#pragma unroll
        for (int m = 0; m < 2; ++m)
#pragma unroll
            for (int rr = 0; rr < 4; ++rr) { maxv[m][rr] = -3.4e38f; maxi[m][rr] = 0; }

        for (int c = 0; c < 16; ++c) {
            const int cur = c & 1;
            if (c < 15) {   // T14 issue-early: next chunk -> regs, in flight under MFMA
                const char* gc = gBi + (size_t)(c + 1) * CHUNK_BYTES;
#pragma unroll
                for (int k = 0; k < 6; ++k)
                    st[k] = *reinterpret_cast<const uint4*>(gc + tid * 16 + k * 4096);
            }
            const char* sbc = sBase + cur * CHUNK_BYTES;
            float nh[4];
#pragma unroll
            for (int sub = 0; sub < 4; ++sub)
                nh[sub] = nrm_i[(c << 6) + (sub << 4) + col];

#pragma unroll
            for (int sub = 0; sub < 4; ++sub) {
                int code = (sub << 4) + col;
                int sw = (code & 7) << 4;
                short8 B[3][2];
#pragma unroll
                for (int s = 0; s < 3; ++s)
#pragma unroll
                    for (int kh = 0; kh < 2; ++kh) {
                        int a = ((code << 7) + (kh << 6) + (g << 4)) ^ sw;
                        B[s][kh] = *reinterpret_cast<const short8*>(sbc + s * 8192 + a);
                    }
                f32x4 acc[2][2];
#pragma unroll
                for (int m = 0; m < 2; ++m)
#pragma unroll
                    for (int rr = 0; rr < 4; ++rr) {
                        acc[m][0][rr] = nh[sub];
                        acc[m][1][rr] = 0.f;
                    }
#pragma unroll
                for (int m = 0; m < 2; ++m)
#pragma unroll
                    for (int kh = 0; kh < 2; ++kh) {
                        acc[m][kh] = __builtin_amdgcn_mfma_f32_16x16x32_bf16(A[0][m][kh], B[0][kh], acc[m][kh], 0, 0, 0);
                        acc[m][kh] = __builtin_amdgcn_mfma_f32_16x16x32_bf16(A[0][m][kh], B[1][kh], acc[m][kh], 0, 0, 0);
                        acc[m][kh] = __builtin_amdgcn_mfma_f32_16x16x32_bf16(A[1][m][kh], B[0][kh], acc[m][kh], 0, 0, 0);
                        acc[m][kh] = __builtin_amdgcn_mfma_f32_16x16x32_bf16(A[0][m][kh], B[2][kh], acc[m][kh], 0, 0, 0);
                        acc[m][kh] = __builtin_amdgcn_mfma_f32_16x16x32_bf16(A[1][m][kh], B[1][kh], acc[m][kh], 0, 0, 0);
                        acc[m][kh] = __builtin_amdgcn_mfma_f32_16x16x32_bf16(A[2][m][kh], B[0][kh], acc[m][kh], 0, 0, 0);
                    }
#pragma unroll
                for (int m = 0; m < 2; ++m)
#pragma unroll
                    for (int rr = 0; rr < 4; ++rr) {
                        float s = acc[m][0][rr] + acc[m][1][rr];   // argmax s == argmin dist
                        if (s > maxv[m][rr]) { maxv[m][rr] = s; maxi[m][rr] = (c << 6) + code; }
                    }
            }
            __syncthreads();
            if (c < 15) {   // write-late into the other buffer
                char* sbn = sBase + (cur ^ 1) * CHUNK_BYTES;
#pragma unroll
                for (int k = 0; k < 6; ++k)
                    *reinterpret_cast<uint4*>(sbn + tid * 16 + k * 4096) = st[k];
                __syncthreads();
            }
        }

        // cross-lane argmax within each 16-lane group, idx tie-break
#pragma unroll
        for (int m = 0; m < 2; ++m)
#pragma unroll
            for (int rr = 0; rr < 4; ++rr) {
                float v = maxv[m][rr]; int ix = maxi[m][rr];
#pragma unroll
                for (int off = 1; off < 16; off <<= 1) {
                    float ov = __shfl_xor(v, off, 64);
                    int   oi = __shfl_xor(ix, off, 64);
                    if (ov > v || (ov == v && oi < ix)) { v = ov; ix = oi; }
                }
                maxi[m][rr] = ix;
            }
        __syncthreads();
        if (col == 0) {   // lane group g holds D-rows g*4+rr
#pragma unroll
            for (int m = 0; m < 2; ++m)
#pragma unroll
                for (int rr = 0; rr < 4; ++rr)
                    sBest[wid][m * 16 + g * 4 + rr] = maxi[m][rr];
        }
        __syncthreads();
        int best[2];
        best[0] = sBest[wid][col];
        best[1] = sBest[wid][16 + col];

        const float* cbi = cb + (size_t)i * NE * DIM;
        if (lane < 16) {  // idx output + histogram, one writer per row
#pragma unroll
            for (int m = 0; m < 2; ++m) {
                int pfr = blockPix + wid * 32 + m * 16 + lane;
                int bb = pfr >> 14, yy = (pfr >> 7) & 127, xx = pfr & 127;
                int bi = sBest[wid][m * 16 + lane];
                size_t off = (size_t)bb * 65536 + (size_t)(yy >> 2) * 2048
                           + (size_t)(xx >> 2) * 64
                           + (size_t)(((yy & 3) << 2) + (xx & 3)) * 4 + (size_t)i;
                out_idx[off] = (float)bi;
                atomicAdd(&hist[i * NE + bi], 1u);
            }
        }

        // residual update from ORIGINAL fp32 codebook (keeps r exact)
#pragma unroll
        for (int m = 0; m < 2; ++m) {
            const float* er = cbi + (size_t)best[m] * DIM;
#pragma unroll
            for (int kh = 0; kh < 2; ++kh) {
                const float4* e4 = reinterpret_cast<const float4*>(er + kh * 32 + g * 8);
                float4 q0 = e4[0], q1 = e4[1];
                r[m][kh][0] -= q0.x; r[m][kh][1] -= q0.y;
                r[m][kh][2] -= q0.z; r[m][kh][3] -= q0.w;
                r[m][kh][4] -= q1.x; r[m][kh][5] -= q1.y;
                r[m][kh][6] -= q1.z; r[m][kh][7] -= q1.w;
            }
        }

        // MSE partial: (z_q - r_old)^2 = r_new^2
        float s = 0.f;
#pragma unroll
        for (int m = 0; m < 2; ++m)
#pragma unroll
            for (int kh = 0; kh < 2; ++kh)
#pragma unroll
                for (int e = 0; e < 8; ++e) s = fmaf(r[m][kh][e], r[m][kh][e], s);
#pragma unroll
        for (int d_ = 32; d_ > 0; d_ >>= 1) s += __shfl_down(s, d_, 64);
        if (lane == 0) msePartial[i * NWAVES + blockIdx.x * 4 + wid] = s;
    }

    // epilogue: z_q = z - r_final (telescoped straight-through sum)
#pragma unroll
    for (int m = 0; m < 2; ++m)
#pragma unroll
        for (int kh = 0; kh < 2; ++kh)
#pragma unroll
            for (int e = 0; e < 8; ++e) {
                size_t o = zb[m] + (size_t)(kh * 32 + g * 8 + e) * HW;
                out_zq[o] = z[o] - r[m][kh][e];
            }
}

// ---------------- kernel 2: deterministic loss finalize ----------------
__global__ __launch_bounds__(1024) void rvq_finalize(
    const unsigned* __restrict__ hist, const float* __restrict__ msePartial,
    float* __restrict__ out_loss)
{
    __shared__ float red[1024];
    int t = threadIdx.x;
    float loss = 0.f;
    for (int i = 0; i < NCB; ++i) {
        float cnt = (float)hist[i * NE + t];
        float prob = (cnt + EPSF) / (131072.0f + EPSF * 1024.0f);
        red[t] = -prob * logf(prob + EPSF);
        __syncthreads();
        for (int s = 512; s > 0; s >>= 1) { if (t < s) red[t] += red[t + s]; __syncthreads(); }
        float entropy = red[0];
        __syncthreads();
        red[t] = msePartial[i * NWAVES + t]        + msePartial[i * NWAVES + 1024 + t]
               + msePartial[i * NWAVES + 2048 + t] + msePartial[i * NWAVES + 3072 + t];
        __syncthreads();
        for (int s = 512; s > 0; s >>= 1) { if (t < s) red[t] += red[t + s]; __syncthreads(); }
        float mse_sum = red[0];
        __syncthreads();
        loss += 0.25f * (mse_sum / MSE_DENOM) + 0.01f * (logf(1024.0f) - entropy);
    }
    if (t == 0) out_loss[0] = loss;
}

extern "C" void kernel_launch(void* const* d_in, const int* in_sizes, int n_in,
                              void* d_out, int out_size, void* d_ws, size_t ws_size,
                              hipStream_t stream) {
    const float* z  = (const float*)d_in[0];
    const float* cb = (const float*)d_in[1];

    float* out      = (float*)d_out;
    float* out_zq   = out;                    // 8388608
    float* out_loss = out + 8388608;          // 1
    float* out_idx  = out + 8388609;          // 524288 (indices as float)

    unsigned* hist        = (unsigned*)d_ws;                        // 16 KB
    float*    nrmh        = (float*)((char*)d_ws + 16384);          // 16 KB
    float*    msePartial  = (float*)((char*)d_ws + 32768);          // 64 KB
    unsigned short* gB    = (unsigned short*)((char*)d_ws + 98304); // 1.5 MB pre-split image

    hipMemsetAsync(d_ws, 0, 16384, stream);   // zero histogram (deterministic)
    rvq_norms<<<64, 64, 0, stream>>>(cb, nrmh);
    rvq_presplit<<<64, 256, 0, stream>>>(cb, gB);
    rvq_main<<<1024, 256, 0, stream>>>(z, gB, nrmh, cb, out_zq, out_idx, hist, msePartial);
    rvq_finalize<<<1, 1024, 0, stream>>>(hist, msePartial, out_loss);
}

// Round 6
// 401.901 us; speedup vs baseline: 1.7983x; 1.7983x over previous
//
#include <hip/hip_runtime.h>
#include <math.h>

typedef __attribute__((ext_vector_type(8))) short short8;
typedef __attribute__((ext_vector_type(4))) float f32x4;

#define NCB 4
#define NE 1024
#define DIM 64
#define HW 16384
#define NPIX 131072
#define NWAVES 4096            // 1024 blocks * 4 waves
#define MSE_DENOM 8388608.0f   // NPIX*DIM
#define EPSF 1e-5f
#define CHUNK_BYTES 24576      // 3 splits * 64 codes * 64 dims * 2B
#define CHUNK_SHORTS 12288

__device__ __forceinline__ unsigned short f2bf(float x) {  // RNE fp32->bf16
    unsigned u = __float_as_uint(x);
    u += 0x7fffu + ((u >> 16) & 1u);
    return (unsigned short)(u >> 16);
}
__device__ __forceinline__ float bf2f(unsigned short h) {  // exact bf16->fp32
    return __uint_as_float(((unsigned)h) << 16);
}

// ------------- kernel 0: -0.5*||e||^2 per code (fp32, exact) -------------
__global__ __launch_bounds__(64) void rvq_norms(const float* __restrict__ cb,
                                                float* __restrict__ nrmh) {
    int code = blockIdx.x * 64 + threadIdx.x;  // 0..4095
    const float4* row = reinterpret_cast<const float4*>(cb + (size_t)code * DIM);
    float s0 = 0.f, s1 = 0.f, s2 = 0.f, s3 = 0.f;
#pragma unroll
    for (int k = 0; k < 16; ++k) {
        float4 v = row[k];
        s0 = fmaf(v.x, v.x, s0); s1 = fmaf(v.y, v.y, s1);
        s2 = fmaf(v.z, v.z, s2); s3 = fmaf(v.w, v.w, s3);
    }
    nrmh[code] = -0.5f * ((s0 + s1) + (s2 + s3));
}

// ------------- kernel 0b: pre-split codebook -> swizzled bf16x3 image ----
// One block per (codebook i, chunk c). Produces the EXACT byte image the
// main kernel's LDS chunk buffer holds (incl. XOR swizzle), so main-loop
// staging is a linear 24KB copy (global_load_lds) with zero split VALU.
__global__ __launch_bounds__(256) void rvq_presplit(const float* __restrict__ cb,
                                                    unsigned short* __restrict__ gB) {
    int blk = blockIdx.x;            // i*16 + c
    int tid = threadIdx.x;
    int code = tid >> 2, dg = tid & 3;
    int c0 = (blk & 15) << 6;
    int i  = blk >> 4;
    const float4* s4 = reinterpret_cast<const float4*>(
        cb + ((size_t)i * NE + c0 + code) * DIM + dg * 16);
    float v[16];
    {
        float4 q;
        q = s4[0]; v[0]=q.x; v[1]=q.y; v[2]=q.z; v[3]=q.w;
        q = s4[1]; v[4]=q.x; v[5]=q.y; v[6]=q.z; v[7]=q.w;
        q = s4[2]; v[8]=q.x; v[9]=q.y; v[10]=q.z; v[11]=q.w;
        q = s4[3]; v[12]=q.x; v[13]=q.y; v[14]=q.z; v[15]=q.w;
    }
    char* outc = reinterpret_cast<char*>(gB + (size_t)blk * CHUNK_SHORTS);
    int linbase = code * 128 + dg * 32;
    int sw = (code & 7) << 4;
#pragma unroll
    for (int h = 0; h < 2; ++h) {
        short8 p1, p2, p3;
#pragma unroll
        for (int e = 0; e < 8; ++e) {
            float t = v[h * 8 + e];
            unsigned short u1 = f2bf(t); t -= bf2f(u1);
            unsigned short u2 = f2bf(t); t -= bf2f(u2);
            unsigned short u3 = f2bf(t);
            p1[e] = (short)u1; p2[e] = (short)u2; p3[e] = (short)u3;
        }
        int a = (linbase + h * 16) ^ sw;
        *reinterpret_cast<short8*>(outc + a)         = p1;
        *reinterpret_cast<short8*>(outc + 8192 + a)  = p2;
        *reinterpret_cast<short8*>(outc + 16384 + a) = p3;
    }
}

// async 16B/lane global->LDS: wave-uniform LDS base, per-lane global src.
__device__ __forceinline__ void gload16(const void* gsrc, void* ldst) {
    __builtin_amdgcn_global_load_lds(
        (const __attribute__((address_space(1))) unsigned int*)gsrc,
        (__attribute__((address_space(3))) unsigned int*)ldst, 16, 0, 0);
}

// ------------- kernel 1: MFMA RVQ, 2-phase global_load_lds pipeline ------
// 1024 blocks x 4 waves; wave owns 32 pixels (2 16-row A-tiles). Per chunk:
// issue next chunk's 6 global_load_lds into the alternate LDS buffer (zero
// staging VGPRs -> no spills, the R5 failure), compute current chunk
// (24 ds_read_b128 + 96 MFMA + max-scan), one __syncthreads (drains vmcnt
// + guards buffer swap). s = r.e - 0.5||e||^2, argmax s == argmin dist;
// ascending-code strict-> scan + idx tie-break = jnp.argmin first-min.
// Numerics bit-identical to the validated R4 kernel.
__global__ __launch_bounds__(256, 2) void rvq_main(
    const float* __restrict__ z, const unsigned short* __restrict__ gB,
    const float* __restrict__ nrmh, const float* __restrict__ cb,
    float* __restrict__ out_zq, float* __restrict__ out_idx,
    unsigned* __restrict__ hist, float* __restrict__ msePartial)
{
    __shared__ uint4 sB[2][CHUNK_BYTES / 16];   // 48 KB double buffer
    __shared__ int   sBest[4][32];

    const int tid  = threadIdx.x;
    const int lane = tid & 63;
    const int wid  = tid >> 6;
    const int col  = lane & 15;   // A-row within tile / D-col (code)
    const int g    = lane >> 4;   // k-group (8 dims) / D row-group
    const int blockPix = blockIdx.x * 128;
    char* sBase = reinterpret_cast<char*>(sB);
    const int stOff = wid * 1024;           // wave's 1KB slice within each 4KB
    const int stLane = stOff + lane * 16;   // per-lane global offset

    int pf[2]; size_t zb[2];
#pragma unroll
    for (int m = 0; m < 2; ++m) {
        pf[m] = blockPix + wid * 32 + m * 16 + col;
        zb[m] = (size_t)(pf[m] >> 14) * 1048576 + (size_t)(pf[m] & 16383);
    }

    float r[2][2][8];   // [m][kh][e], dim = kh*32 + g*8 + e
#pragma unroll
    for (int m = 0; m < 2; ++m)
#pragma unroll
        for (int kh = 0; kh < 2; ++kh)
#pragma unroll
            for (int e = 0; e < 8; ++e)
                r[m][kh][e] = z[zb[m] + (size_t)(kh * 32 + g * 8 + e) * HW];

    for (int i = 0; i < NCB; ++i) {
        const char* gBi = reinterpret_cast<const char*>(gB) + (size_t)i * 16 * CHUNK_BYTES;
        const float* nrm_i = nrmh + i * NE;

        // bf16x3 split of r -> A-frags (32 values, once per codebook)
        short8 A[3][2][2];
#pragma unroll
        for (int m = 0; m < 2; ++m)
#pragma unroll
            for (int kh = 0; kh < 2; ++kh)
#pragma unroll
                for (int e = 0; e < 8; ++e) {
                    float t = r[m][kh][e];
                    unsigned short u1 = f2bf(t); t -= bf2f(u1);
                    unsigned short u2 = f2bf(t); t -= bf2f(u2);
                    unsigned short u3 = f2bf(t);
                    A[0][m][kh][e] = (short)u1;
                    A[1][m][kh][e] = (short)u2;
                    A[2][m][kh][e] = (short)u3;
                }

        // prologue: stage chunk 0 into buffer 0 (async, drained by barrier)
#pragma unroll
        for (int k = 0; k < 6; ++k)
            gload16(gBi + k * 4096 + stLane, sBase + k * 4096 + stOff);
        __syncthreads();

        float maxv[2][4]; int maxi[2][4];
#pragma unroll
        for (int m = 0; m < 2; ++m)
#pragma unroll
            for (int rr = 0; rr < 4; ++rr) { maxv[m][rr] = -3.4e38f; maxi[m][rr] = 0; }

        for (int c = 0; c < 16; ++c) {
            const int cur = c & 1;
            if (c < 15) {   // issue next chunk into alternate buffer (async)
                const char* gc = gBi + (size_t)(c + 1) * CHUNK_BYTES;
                char* sbn = sBase + (cur ^ 1) * CHUNK_BYTES;
#pragma unroll
                for (int k = 0; k < 6; ++k)
                    gload16(gc + k * 4096 + stLane, sbn + k * 4096 + stOff);
            }
            const char* sbc = sBase + cur * CHUNK_BYTES;
            float nh[4];
#pragma unroll
            for (int sub = 0; sub < 4; ++sub)
                nh[sub] = nrm_i[(c << 6) + (sub << 4) + col];

#pragma unroll
            for (int sub = 0; sub < 4; ++sub) {
                int code = (sub << 4) + col;
                int sw = (code & 7) << 4;
                short8 B[3][2];
#pragma unroll
                for (int s = 0; s < 3; ++s)
#pragma unroll
                    for (int kh = 0; kh < 2; ++kh) {
                        int a = ((code << 7) + (kh << 6) + (g << 4)) ^ sw;
                        B[s][kh] = *reinterpret_cast<const short8*>(sbc + s * 8192 + a);
                    }
                f32x4 acc[2][2];
#pragma unroll
                for (int m = 0; m < 2; ++m)
#pragma unroll
                    for (int rr = 0; rr < 4; ++rr) {
                        acc[m][0][rr] = nh[sub];
                        acc[m][1][rr] = 0.f;
                    }
#pragma unroll
                for (int m = 0; m < 2; ++m)
#pragma unroll
                    for (int kh = 0; kh < 2; ++kh) {
                        acc[m][kh] = __builtin_amdgcn_mfma_f32_16x16x32_bf16(A[0][m][kh], B[0][kh], acc[m][kh], 0, 0, 0);
                        acc[m][kh] = __builtin_amdgcn_mfma_f32_16x16x32_bf16(A[0][m][kh], B[1][kh], acc[m][kh], 0, 0, 0);
                        acc[m][kh] = __builtin_amdgcn_mfma_f32_16x16x32_bf16(A[1][m][kh], B[0][kh], acc[m][kh], 0, 0, 0);
                        acc[m][kh] = __builtin_amdgcn_mfma_f32_16x16x32_bf16(A[0][m][kh], B[2][kh], acc[m][kh], 0, 0, 0);
                        acc[m][kh] = __builtin_amdgcn_mfma_f32_16x16x32_bf16(A[1][m][kh], B[1][kh], acc[m][kh], 0, 0, 0);
                        acc[m][kh] = __builtin_amdgcn_mfma_f32_16x16x32_bf16(A[2][m][kh], B[0][kh], acc[m][kh], 0, 0, 0);
                    }
#pragma unroll
                for (int m = 0; m < 2; ++m)
#pragma unroll
                    for (int rr = 0; rr < 4; ++rr) {
                        float s = acc[m][0][rr] + acc[m][1][rr];   // argmax s == argmin dist
                        if (s > maxv[m][rr]) { maxv[m][rr] = s; maxi[m][rr] = (c << 6) + code; }
                    }
            }
            __syncthreads();   // drains prefetch vmcnt + guards buffer reuse
        }

        // cross-lane argmax within each 16-lane group, idx tie-break
#pragma unroll
        for (int m = 0; m < 2; ++m)
#pragma unroll
            for (int rr = 0; rr < 4; ++rr) {
                float v = maxv[m][rr]; int ix = maxi[m][rr];
#pragma unroll
                for (int off = 1; off < 16; off <<= 1) {
                    float ov = __shfl_xor(v, off, 64);
                    int   oi = __shfl_xor(ix, off, 64);
                    if (ov > v || (ov == v && oi < ix)) { v = ov; ix = oi; }
                }
                maxi[m][rr] = ix;
            }
        __syncthreads();
        if (col == 0) {   // lane group g holds D-rows g*4+rr
#pragma unroll
            for (int m = 0; m < 2; ++m)
#pragma unroll
                for (int rr = 0; rr < 4; ++rr)
                    sBest[wid][m * 16 + g * 4 + rr] = maxi[m][rr];
        }
        __syncthreads();
        int best[2];
        best[0] = sBest[wid][col];
        best[1] = sBest[wid][16 + col];

        const float* cbi = cb + (size_t)i * NE * DIM;
        if (lane < 16) {  // idx output + histogram, one writer per row
#pragma unroll
            for (int m = 0; m < 2; ++m) {
                int pfr = blockPix + wid * 32 + m * 16 + lane;
                int bb = pfr >> 14, yy = (pfr >> 7) & 127, xx = pfr & 127;
                int bi = sBest[wid][m * 16 + lane];
                size_t off = (size_t)bb * 65536 + (size_t)(yy >> 2) * 2048
                           + (size_t)(xx >> 2) * 64
                           + (size_t)(((yy & 3) << 2) + (xx & 3)) * 4 + (size_t)i;
                out_idx[off] = (float)bi;
                atomicAdd(&hist[i * NE + bi], 1u);
            }
        }

        // residual update from ORIGINAL fp32 codebook (keeps r exact)
#pragma unroll
        for (int m = 0; m < 2; ++m) {
            const float* er = cbi + (size_t)best[m] * DIM;
#pragma unroll
            for (int kh = 0; kh < 2; ++kh) {
                const float4* e4 = reinterpret_cast<const float4*>(er + kh * 32 + g * 8);
                float4 q0 = e4[0], q1 = e4[1];
                r[m][kh][0] -= q0.x; r[m][kh][1] -= q0.y;
                r[m][kh][2] -= q0.z; r[m][kh][3] -= q0.w;
                r[m][kh][4] -= q1.x; r[m][kh][5] -= q1.y;
                r[m][kh][6] -= q1.z; r[m][kh][7] -= q1.w;
            }
        }

        // MSE partial: (z_q - r_old)^2 = r_new^2
        float s = 0.f;
#pragma unroll
        for (int m = 0; m < 2; ++m)
#pragma unroll
            for (int kh = 0; kh < 2; ++kh)
#pragma unroll
                for (int e = 0; e < 8; ++e) s = fmaf(r[m][kh][e], r[m][kh][e], s);
#pragma unroll
        for (int d_ = 32; d_ > 0; d_ >>= 1) s += __shfl_down(s, d_, 64);
        if (lane == 0) msePartial[i * NWAVES + blockIdx.x * 4 + wid] = s;
    }

    // epilogue: z_q = z - r_final (telescoped straight-through sum)
#pragma unroll
    for (int m = 0; m < 2; ++m)
#pragma unroll
        for (int kh = 0; kh < 2; ++kh)
#pragma unroll
            for (int e = 0; e < 8; ++e) {
                size_t o = zb[m] + (size_t)(kh * 32 + g * 8 + e) * HW;
                out_zq[o] = z[o] - r[m][kh][e];
            }
}

// ---------------- kernel 2: deterministic loss finalize ----------------
__global__ __launch_bounds__(1024) void rvq_finalize(
    const unsigned* __restrict__ hist, const float* __restrict__ msePartial,
    float* __restrict__ out_loss)
{
    __shared__ float red[1024];
    int t = threadIdx.x;
    float loss = 0.f;
    for (int i = 0; i < NCB; ++i) {
        float cnt = (float)hist[i * NE + t];
        float prob = (cnt + EPSF) / (131072.0f + EPSF * 1024.0f);
        red[t] = -prob * logf(prob + EPSF);
        __syncthreads();
        for (int s = 512; s > 0; s >>= 1) { if (t < s) red[t] += red[t + s]; __syncthreads(); }
        float entropy = red[0];
        __syncthreads();
        red[t] = msePartial[i * NWAVES + t]        + msePartial[i * NWAVES + 1024 + t]
               + msePartial[i * NWAVES + 2048 + t] + msePartial[i * NWAVES + 3072 + t];
        __syncthreads();
        for (int s = 512; s > 0; s >>= 1) { if (t < s) red[t] += red[t + s]; __syncthreads(); }
        float mse_sum = red[0];
        __syncthreads();
        loss += 0.25f * (mse_sum / MSE_DENOM) + 0.01f * (logf(1024.0f) - entropy);
    }
    if (t == 0) out_loss[0] = loss;
}

extern "C" void kernel_launch(void* const* d_in, const int* in_sizes, int n_in,
                              void* d_out, int out_size, void* d_ws, size_t ws_size,
                              hipStream_t stream) {
    const float* z  = (const float*)d_in[0];
    const float* cb = (const float*)d_in[1];

    float* out      = (float*)d_out;
    float* out_zq   = out;                    // 8388608
    float* out_loss = out + 8388608;          // 1
    float* out_idx  = out + 8388609;          // 524288 (indices as float)

    unsigned* hist        = (unsigned*)d_ws;                        // 16 KB
    float*    nrmh        = (float*)((char*)d_ws + 16384);          // 16 KB
    float*    msePartial  = (float*)((char*)d_ws + 32768);          // 64 KB
    unsigned short* gB    = (unsigned short*)((char*)d_ws + 98304); // 1.5 MB pre-split image

    hipMemsetAsync(d_ws, 0, 16384, stream);   // zero histogram (deterministic)
    rvq_norms<<<64, 64, 0, stream>>>(cb, nrmh);
    rvq_presplit<<<64, 256, 0, stream>>>(cb, gB);
    rvq_main<<<1024, 256, 0, stream>>>(z, gB, nrmh, cb, out_zq, out_idx, hist, msePartial);
    rvq_finalize<<<1, 1024, 0, stream>>>(hist, msePartial, out_loss);
}

// Round 7
// 382.950 us; speedup vs baseline: 1.8873x; 1.0495x over previous
//
#include <hip/hip_runtime.h>
#include <math.h>

typedef __attribute__((ext_vector_type(8))) short short8;
typedef __attribute__((ext_vector_type(4))) float f32x4;

#define NCB 4
#define NE 1024
#define DIM 64
#define HW 16384
#define NPIX 131072
#define NWAVES 4096            // 1024 blocks * 4 waves
#define MSE_DENOM 8388608.0f   // NPIX*DIM
#define EPSF 1e-5f
#define CHUNK_BYTES 12288      // 3 splits * 32 codes * 64 dims * 2B
#define NCHUNK 32              // half-chunks per codebook

__device__ __forceinline__ unsigned short f2bf(float x) {  // RNE fp32->bf16
    unsigned u = __float_as_uint(x);
    u += 0x7fffu + ((u >> 16) & 1u);
    return (unsigned short)(u >> 16);
}
__device__ __forceinline__ float bf2f(unsigned short h) {  // exact bf16->fp32
    return __uint_as_float(((unsigned)h) << 16);
}

// ------------- kernel 0: -0.5*||e||^2 per code (fp32, exact) -------------
__global__ __launch_bounds__(64) void rvq_norms(const float* __restrict__ cb,
                                                float* __restrict__ nrmh) {
    int code = blockIdx.x * 64 + threadIdx.x;  // 0..4095
    const float4* row = reinterpret_cast<const float4*>(cb + (size_t)code * DIM);
    float s0 = 0.f, s1 = 0.f, s2 = 0.f, s3 = 0.f;
#pragma unroll
    for (int k = 0; k < 16; ++k) {
        float4 v = row[k];
        s0 = fmaf(v.x, v.x, s0); s1 = fmaf(v.y, v.y, s1);
        s2 = fmaf(v.z, v.z, s2); s3 = fmaf(v.w, v.w, s3);
    }
    nrmh[code] = -0.5f * ((s0 + s1) + (s2 + s3));
}

// ------------- kernel 0b: pre-split codebook -> swizzled bf16x3 image ----
// Image layout: [cb i][chunk c(32 codes)][split(3)][code(32)x dim(64) swz].
// Byte-identical to the main kernel's 12KB LDS chunk buffer.
__global__ __launch_bounds__(256) void rvq_presplit(const float* __restrict__ cb,
                                                    unsigned short* __restrict__ gB) {
    int blk = blockIdx.x;            // i*16 + c64
    int tid = threadIdx.x;
    int code64 = tid >> 2, dg = tid & 3;
    int c0 = (blk & 15) << 6;
    int i  = blk >> 4;
    const float4* s4 = reinterpret_cast<const float4*>(
        cb + ((size_t)i * NE + c0 + code64) * DIM + dg * 16);
    float v[16];
    {
        float4 q;
        q = s4[0]; v[0]=q.x; v[1]=q.y; v[2]=q.z; v[3]=q.w;
        q = s4[1]; v[4]=q.x; v[5]=q.y; v[6]=q.z; v[7]=q.w;
        q = s4[2]; v[8]=q.x; v[9]=q.y; v[10]=q.z; v[11]=q.w;
        q = s4[3]; v[12]=q.x; v[13]=q.y; v[14]=q.z; v[15]=q.w;
    }
    int chunk = (blk & 15) * 2 + (code64 >> 5);   // within codebook
    int j = code64 & 31;                          // code within chunk
    char* outc = reinterpret_cast<char*>(gB)
               + ((size_t)i * NCHUNK + chunk) * CHUNK_BYTES;
    int linbase = j * 128 + dg * 32;
    int sw = (j & 7) << 4;
#pragma unroll
    for (int h = 0; h < 2; ++h) {
        short8 p1, p2, p3;
#pragma unroll
        for (int e = 0; e < 8; ++e) {
            float t = v[h * 8 + e];
            unsigned short u1 = f2bf(t); t -= bf2f(u1);
            unsigned short u2 = f2bf(t); t -= bf2f(u2);
            unsigned short u3 = f2bf(t);
            p1[e] = (short)u1; p2[e] = (short)u2; p3[e] = (short)u3;
        }
        int a = (linbase + h * 16) ^ sw;
        *reinterpret_cast<short8*>(outc + a)        = p1;
        *reinterpret_cast<short8*>(outc + 4096 + a) = p2;
        *reinterpret_cast<short8*>(outc + 8192 + a) = p3;
    }
}

// async 16B/lane global->LDS: wave-uniform LDS base, per-lane global src.
__device__ __forceinline__ void gload16(const void* gsrc, void* ldst) {
    __builtin_amdgcn_global_load_lds(
        (const __attribute__((address_space(1))) unsigned int*)gsrc,
        (__attribute__((address_space(3))) unsigned int*)ldst, 16, 0, 0);
}

// ------------- kernel 1: MFMA RVQ, half-chunk high-occupancy pipeline ----
// 1024 blocks x 4 waves, 24.5KB LDS + 128 VGPR -> 4 blocks/CU (16 waves,
// 4/SIMD; whole grid resident). Per 32-code chunk: issue 3 gload_lds into
// the alternate 12KB buffer, compute 2 subs x (6 ds_read_b128 + 24 MFMA,
// K-halves CHAINED into one acc = fewer inits/adds/regs), barrier.
// s = r.e - 0.5||e||^2 accumulated in-MFMA; argmax s == argmin dist;
// ascending-code strict-> scan + idx tie-break = jnp.argmin first-min.
__global__ __launch_bounds__(256, 4) void rvq_main(
    const float* __restrict__ z, const unsigned short* __restrict__ gB,
    const float* __restrict__ nrmh, const float* __restrict__ cb,
    float* __restrict__ out_zq, float* __restrict__ out_idx,
    unsigned* __restrict__ hist, float* __restrict__ msePartial)
{
    __shared__ uint4 sB[2][CHUNK_BYTES / 16];   // 24 KB double buffer
    __shared__ int   sBest[4][32];

    const int tid  = threadIdx.x;
    const int lane = tid & 63;
    const int wid  = tid >> 6;
    const int col  = lane & 15;   // A-row within tile / D-col (code)
    const int g    = lane >> 4;   // k-group (8 dims) / D row-group
    const int blockPix = blockIdx.x * 128;
    char* sBase = reinterpret_cast<char*>(sB);
    const int sw = (col & 7) << 4;

    size_t zb[2];
#pragma unroll
    for (int m = 0; m < 2; ++m) {
        int pf = blockPix + wid * 32 + m * 16 + col;
        zb[m] = (size_t)(pf >> 14) * 1048576 + (size_t)(pf & 16383);
    }

    float r[2][2][8];   // [m][kh][e], dim = kh*32 + g*8 + e
#pragma unroll
    for (int m = 0; m < 2; ++m)
#pragma unroll
        for (int kh = 0; kh < 2; ++kh)
#pragma unroll
            for (int e = 0; e < 8; ++e)
                r[m][kh][e] = z[zb[m] + (size_t)(kh * 32 + g * 8 + e) * HW];

    for (int i = 0; i < NCB; ++i) {
        const char* gBi = reinterpret_cast<const char*>(gB) + (size_t)i * NCHUNK * CHUNK_BYTES;
        const float* nrm_i = nrmh + i * NE;

        // bf16x3 split of r -> A-frags (once per codebook)
        short8 A[3][2][2];
#pragma unroll
        for (int m = 0; m < 2; ++m)
#pragma unroll
            for (int kh = 0; kh < 2; ++kh)
#pragma unroll
                for (int e = 0; e < 8; ++e) {
                    float t = r[m][kh][e];
                    unsigned short u1 = f2bf(t); t -= bf2f(u1);
                    unsigned short u2 = f2bf(t); t -= bf2f(u2);
                    unsigned short u3 = f2bf(t);
                    A[0][m][kh][e] = (short)u1;
                    A[1][m][kh][e] = (short)u2;
                    A[2][m][kh][e] = (short)u3;
                }

        // prologue: stage chunk 0 into buffer 0 (async, drained by barrier)
#pragma unroll
        for (int k = 0; k < 3; ++k)
            gload16(gBi + k * 4096 + tid * 16, sBase + k * 4096 + tid * 16);
        __syncthreads();

        float maxv[2][4]; int maxi[2][4];
#pragma unroll
        for (int m = 0; m < 2; ++m)
#pragma unroll
            for (int rr = 0; rr < 4; ++rr) { maxv[m][rr] = -3.4e38f; maxi[m][rr] = 0; }

        for (int c = 0; c < NCHUNK; ++c) {
            const int cur = c & 1;
            if (c < NCHUNK - 1) {   // issue next chunk into alternate buffer
                const char* gc = gBi + (size_t)(c + 1) * CHUNK_BYTES;
                char* sbn = sBase + (cur ^ 1) * CHUNK_BYTES;
#pragma unroll
                for (int k = 0; k < 3; ++k)
                    gload16(gc + k * 4096 + tid * 16, sbn + k * 4096 + tid * 16);
            }
            const char* sbc = sBase + cur * CHUNK_BYTES;

#pragma unroll
            for (int sub = 0; sub < 2; ++sub) {
                const int code = (sub << 4) + col;
                float nh = nrm_i[(c << 5) + code];
                f32x4 acc[2];
#pragma unroll
                for (int rr = 0; rr < 4; ++rr) { acc[0][rr] = nh; acc[1][rr] = nh; }

                __builtin_amdgcn_s_setprio(1);
#pragma unroll
                for (int sb = 0; sb < 3; ++sb) {   // B-split-major: 4 B regs live
                    short8 B0 = *reinterpret_cast<const short8*>(
                        sbc + sb * 4096 + ((((code << 7) + (g << 4))) ^ sw));
                    short8 B1 = *reinterpret_cast<const short8*>(
                        sbc + sb * 4096 + ((((code << 7) + 64 + (g << 4))) ^ sw));
#pragma unroll
                    for (int sa = 0; sa < 3 - sb; ++sa) {   // products with sa+sb<=2
                        acc[0] = __builtin_amdgcn_mfma_f32_16x16x32_bf16(A[sa][0][0], B0, acc[0], 0, 0, 0);
                        acc[1] = __builtin_amdgcn_mfma_f32_16x16x32_bf16(A[sa][1][0], B0, acc[1], 0, 0, 0);
                        acc[0] = __builtin_amdgcn_mfma_f32_16x16x32_bf16(A[sa][0][1], B1, acc[0], 0, 0, 0);
                        acc[1] = __builtin_amdgcn_mfma_f32_16x16x32_bf16(A[sa][1][1], B1, acc[1], 0, 0, 0);
                    }
                }
                __builtin_amdgcn_s_setprio(0);

#pragma unroll
                for (int m = 0; m < 2; ++m)
#pragma unroll
                    for (int rr = 0; rr < 4; ++rr) {
                        float s = acc[m][rr];          // argmax s == argmin dist
                        if (s > maxv[m][rr]) { maxv[m][rr] = s; maxi[m][rr] = (c << 5) + code; }
                    }
            }
            __syncthreads();   // drains prefetch vmcnt + guards buffer reuse
        }

        // cross-lane argmax within each 16-lane group, idx tie-break
#pragma unroll
        for (int m = 0; m < 2; ++m)
#pragma unroll
            for (int rr = 0; rr < 4; ++rr) {
                float v = maxv[m][rr]; int ix = maxi[m][rr];
#pragma unroll
                for (int off = 1; off < 16; off <<= 1) {
                    float ov = __shfl_xor(v, off, 64);
                    int   oi = __shfl_xor(ix, off, 64);
                    if (ov > v || (ov == v && oi < ix)) { v = ov; ix = oi; }
                }
                maxi[m][rr] = ix;
            }
        __syncthreads();
        if (col == 0) {   // lane group g holds D-rows g*4+rr
#pragma unroll
            for (int m = 0; m < 2; ++m)
#pragma unroll
                for (int rr = 0; rr < 4; ++rr)
                    sBest[wid][m * 16 + g * 4 + rr] = maxi[m][rr];
        }
        __syncthreads();
        int best[2];
        best[0] = sBest[wid][col];
        best[1] = sBest[wid][16 + col];

        const float* cbi = cb + (size_t)i * NE * DIM;
        if (lane < 16) {  // idx output + histogram, one writer per row
#pragma unroll
            for (int m = 0; m < 2; ++m) {
                int pfr = blockPix + wid * 32 + m * 16 + lane;
                int bb = pfr >> 14, yy = (pfr >> 7) & 127, xx = pfr & 127;
                int bi = sBest[wid][m * 16 + lane];
                size_t off = (size_t)bb * 65536 + (size_t)(yy >> 2) * 2048
                           + (size_t)(xx >> 2) * 64
                           + (size_t)(((yy & 3) << 2) + (xx & 3)) * 4 + (size_t)i;
                out_idx[off] = (float)bi;
                atomicAdd(&hist[i * NE + bi], 1u);
            }
        }

        // residual update from ORIGINAL fp32 codebook (keeps r exact)
#pragma unroll
        for (int m = 0; m < 2; ++m) {
            const float* er = cbi + (size_t)best[m] * DIM;
#pragma unroll
            for (int kh = 0; kh < 2; ++kh) {
                const float4* e4 = reinterpret_cast<const float4*>(er + kh * 32 + g * 8);
                float4 q0 = e4[0], q1 = e4[1];
                r[m][kh][0] -= q0.x; r[m][kh][1] -= q0.y;
                r[m][kh][2] -= q0.z; r[m][kh][3] -= q0.w;
                r[m][kh][4] -= q1.x; r[m][kh][5] -= q1.y;
                r[m][kh][6] -= q1.z; r[m][kh][7] -= q1.w;
            }
        }

        // MSE partial: (z_q - r_old)^2 = r_new^2
        float s = 0.f;
#pragma unroll
        for (int m = 0; m < 2; ++m)
#pragma unroll
            for (int kh = 0; kh < 2; ++kh)
#pragma unroll
                for (int e = 0; e < 8; ++e) s = fmaf(r[m][kh][e], r[m][kh][e], s);
#pragma unroll
        for (int d_ = 32; d_ > 0; d_ >>= 1) s += __shfl_down(s, d_, 64);
        if (lane == 0) msePartial[i * NWAVES + blockIdx.x * 4 + wid] = s;
    }

    // epilogue: z_q = z - r_final (telescoped straight-through sum)
#pragma unroll
    for (int m = 0; m < 2; ++m)
#pragma unroll
        for (int kh = 0; kh < 2; ++kh)
#pragma unroll
            for (int e = 0; e < 8; ++e) {
                size_t o = zb[m] + (size_t)(kh * 32 + g * 8 + e) * HW;
                out_zq[o] = z[o] - r[m][kh][e];
            }
}

// ---------------- kernel 2: deterministic loss finalize ----------------
__global__ __launch_bounds__(1024) void rvq_finalize(
    const unsigned* __restrict__ hist, const float* __restrict__ msePartial,
    float* __restrict__ out_loss)
{
    __shared__ float red[1024];
    int t = threadIdx.x;
    float loss = 0.f;
    for (int i = 0; i < NCB; ++i) {
        float cnt = (float)hist[i * NE + t];
        float prob = (cnt + EPSF) / (131072.0f + EPSF * 1024.0f);
        red[t] = -prob * logf(prob + EPSF);
        __syncthreads();
        for (int s = 512; s > 0; s >>= 1) { if (t < s) red[t] += red[t + s]; __syncthreads(); }
        float entropy = red[0];
        __syncthreads();
        red[t] = msePartial[i * NWAVES + t]        + msePartial[i * NWAVES + 1024 + t]
               + msePartial[i * NWAVES + 2048 + t] + msePartial[i * NWAVES + 3072 + t];
        __syncthreads();
        for (int s = 512; s > 0; s >>= 1) { if (t < s) red[t] += red[t + s]; __syncthreads(); }
        float mse_sum = red[0];
        __syncthreads();
        loss += 0.25f * (mse_sum / MSE_DENOM) + 0.01f * (logf(1024.0f) - entropy);
    }
    if (t == 0) out_loss[0] = loss;
}

extern "C" void kernel_launch(void* const* d_in, const int* in_sizes, int n_in,
                              void* d_out, int out_size, void* d_ws, size_t ws_size,
                              hipStream_t stream) {
    const float* z  = (const float*)d_in[0];
    const float* cb = (const float*)d_in[1];

    float* out      = (float*)d_out;
    float* out_zq   = out;                    // 8388608
    float* out_loss = out + 8388608;          // 1
    float* out_idx  = out + 8388609;          // 524288 (indices as float)

    unsigned* hist        = (unsigned*)d_ws;                        // 16 KB
    float*    nrmh        = (float*)((char*)d_ws + 16384);          // 16 KB
    float*    msePartial  = (float*)((char*)d_ws + 32768);          // 64 KB
    unsigned short* gB    = (unsigned short*)((char*)d_ws + 98304); // 1.5 MB pre-split image

    hipMemsetAsync(d_ws, 0, 16384, stream);   // zero histogram (deterministic)
    rvq_norms<<<64, 64, 0, stream>>>(cb, nrmh);
    rvq_presplit<<<64, 256, 0, stream>>>(cb, gB);
    rvq_main<<<1024, 256, 0, stream>>>(z, gB, nrmh, cb, out_zq, out_idx, hist, msePartial);
    rvq_finalize<<<1, 1024, 0, stream>>>(hist, msePartial, out_loss);
}